// Round 14
// baseline (96.604 us; speedup 1.0000x reference)
//
#include <hip/hip_runtime.h>

#define B_  16
#define TQ  128
#define TK  256
#define DIN 64
#define H_  256
#define DV  256
#define HT  8          // h-cols per proj_k block
#define QT  4          // q-rows per attn block
#define NW  8          // waves per attn block (512 threads)
#define NEG -1000000.0f

// tanh(x) = 1 - 2*rcp(1 + e^{2x});  e^{2x} = exp2(SCALE*x), SCALE = 2*log2(e).
// Factorized: e^{2(q+k)} = Eq*Ek, both precomputed -> hot loop has NO exp, NO LDS.
// Reciprocals batched 2-way: 1/a = b*rcp(ab), 1/b = a*rcp(ab) -> half the v_rcp.
// Two-mode phase 1: vl<=128 -> lanes cover 2 k's (half the per-iter work, all waves busy).
#define SCALE  2.8853900817779268f
#define LOG2E  1.4426950408889634f

typedef float v2f __attribute__((ext_vector_type(2)));

__device__ inline float fast_exp2(float x) { return __builtin_amdgcn_exp2f(x); }
__device__ inline float fast_rcp(float x)  { return __builtin_amdgcn_rcpf(x); }
__device__ inline v2f v2fma(v2f a, v2f b, v2f c) {      // -> v_pk_fma_f32
    return __builtin_elementwise_fma(a, b, c);
}

// ---------------- Kernel B (fused producers) ----------------
// blocks 0..511:    EkT[b,h,k] = exp2(SCALE * sum_d keys[b,k,d]*wk[d,h])   (t = k)
// blocks 512..1023: EqW[b,g,h] = float4 of exp2(SCALE * qproj) for rows 4g..4g+3 (t = h)
__global__ __launch_bounds__(256) void proj_kernel(
    const float* __restrict__ keys, const float* __restrict__ wk,
    const float* __restrict__ queries, const float* __restrict__ wq,
    float* __restrict__ EkT, float4* __restrict__ EqW,
    const int* __restrict__ valid_lens)
{
    int bx = blockIdx.x;
    int t  = threadIdx.x;
    if (bx < 512) {
        // ---- K-projection -> exp, transposed [b][h][k] ----
        int b  = bx >> 5;                // H_/HT == 32
        int h0 = (bx & 31) * HT;
        int vlC = (valid_lens[b] + 63) & ~63;
        if (t >= vlC) return;            // wave-uniform exit; skipped entries stay
                                         // poisoned (finite) and are masked later
        const float4* krow4 = (const float4*)(keys + (size_t)(b * TK + t) * DIN);
        float acc[HT];
        #pragma unroll
        for (int hh = 0; hh < HT; ++hh) acc[hh] = 0.f;
        #pragma unroll 4
        for (int d4 = 0; d4 < DIN / 4; ++d4) {
            float4 kd = krow4[d4];
            const float* wrow = wk + 4 * d4 * H_ + h0;
            #pragma unroll
            for (int hh = 0; hh < HT; ++hh) acc[hh] = fmaf(kd.x, wrow[hh], acc[hh]);
            #pragma unroll
            for (int hh = 0; hh < HT; ++hh) acc[hh] = fmaf(kd.y, wrow[H_ + hh], acc[hh]);
            #pragma unroll
            for (int hh = 0; hh < HT; ++hh) acc[hh] = fmaf(kd.z, wrow[2 * H_ + hh], acc[hh]);
            #pragma unroll
            for (int hh = 0; hh < HT; ++hh) acc[hh] = fmaf(kd.w, wrow[3 * H_ + hh], acc[hh]);
        }
        #pragma unroll
        for (int hh = 0; hh < HT; ++hh)
            EkT[(b * H_ + h0 + hh) * TK + t] = fast_exp2(acc[hh] * SCALE);
    } else {
        // ---- Q-projection -> exp, packed 4 rows per float4, [b][g][h] ----
        int i = bx - 512;                // 0..511
        int b = i >> 5;                  // TQ/QT == 32 groups
        int g = i & 31;
        const float* qbase = queries + (size_t)(b * TQ + 4 * g) * DIN;  // uniform
        float a0 = 0.f, a1 = 0.f, a2 = 0.f, a3 = 0.f;
        #pragma unroll
        for (int d = 0; d < DIN; ++d) {
            float ww = wq[d * H_ + t];               // coalesced, L2-hot
            a0 = fmaf(qbase[d],           ww, a0);   // uniform -> scalar loads
            a1 = fmaf(qbase[DIN + d],     ww, a1);
            a2 = fmaf(qbase[2 * DIN + d], ww, a2);
            a3 = fmaf(qbase[3 * DIN + d], ww, a3);
        }
        EqW[(size_t)(b * 32 + g) * H_ + t] =
            make_float4(fast_exp2(a0 * SCALE), fast_exp2(a1 * SCALE),
                        fast_exp2(a2 * SCALE), fast_exp2(a3 * SCALE));
    }
}

__device__ inline float waveMax(float v) {
    #pragma unroll
    for (int off = 32; off > 0; off >>= 1) v = fmaxf(v, __shfl_xor(v, off, 64));
    return v;
}
__device__ inline float waveSum(float v) {
    #pragma unroll
    for (int off = 32; off > 0; off >>= 1) v += __shfl_xor(v, off, 64);
    return v;
}

// ---------------- Kernel C: scores(4 rows) + softmax + attn@V ----------------
// grid = B*(TQ/QT) = 512 blocks, 512 threads.
// Phase 1: wave w covers h in [32w,32w+32). Wide mode (vl>128): lane l covers
// k=4l..4l+3. Narrow mode (vl<=128): lane l covers k=2l,2l+1 -> half the per-iter
// work, same iteration count, all waves busy (critical path scales with vl-class).
__global__ __launch_bounds__(512, 4) void attn_kernel(
    const float4* __restrict__ EqW, const float* __restrict__ EkT,
    const float* __restrict__ values, const int* __restrict__ valid_lens,
    const float* __restrict__ wv, float* __restrict__ out)
{
    __shared__ float scoreP[NW][QT][TK];   // 32 KB partials of wv*r; [0] reused ph3
    __shared__ float attnT[TK][QT];        // k-major, float4-readable per k

    // XCD swizzle: 2 batches per XCD slot -> ~1 MB hot set per XCD L2.
    int bx  = blockIdx.x;
    int xcd = bx & 7;
    int i   = bx >> 3;                     // 0..63
    int b   = xcd + 8 * (i & 1);
    int g   = i >> 1;                      // q-group 0..31; q0 = 4g
    int q0  = g * QT;
    int t   = threadIdx.x;                 // 0..511
    int w   = t >> 6, l = t & 63;
    int vl  = valid_lens[b];

    // ---- phase 1 ----
    {
        const float4* eqb = EqW + (size_t)(b * 32 + g) * H_;    // block-uniform
        int h0 = __builtin_amdgcn_readfirstlane(w) * (H_ / NW); // SGPR -> uniform idx
        const v2f one2 = {1.f, 1.f};

        // one tanh-partial term for a k-pair: d=1+eq*ek (pk), 1 rcp per 2 elems
        auto pair = [&](float eq, v2f k2, v2f w2, v2f& sp) {
            v2f e2 = {eq, eq};
            v2f d  = v2fma(e2, k2, one2);              // v_pk_fma_f32
            float rp = fast_rcp(d.x * d.y);            // 1 v_rcp per 2 elems
            v2f r  = (v2f){d.y, d.x} * (v2f){rp, rp};  // v_pk_mul_f32
            sp = v2fma(w2, r, sp);                     // v_pk_fma_f32
        };

        if (vl > TK / 2) {
            // ---- wide: lane l covers k=4l..4l+3 ----
            const float4* ek4 = (const float4*)(EkT + (size_t)b * H_ * TK);
            v2f sA0={0,0}, sA1={0,0}, sB0={0,0}, sB1={0,0};
            v2f sC0={0,0}, sC1={0,0}, sD0={0,0}, sD1={0,0};

            auto body = [&](int h, float4 kv) {
                float4 eq  = eqb[h];                   // uniform -> s_load_dwordx4
                float  wvh = wv[h];                    // uniform -> s_load_dword
                v2f w2  = {wvh, wvh};
                v2f kxy = {kv.x, kv.y};
                v2f kzw = {kv.z, kv.w};
                pair(eq.x, kxy, w2, sA0); pair(eq.x, kzw, w2, sA1);
                pair(eq.y, kxy, w2, sB0); pair(eq.y, kzw, w2, sB1);
                pair(eq.z, kxy, w2, sC0); pair(eq.z, kzw, w2, sC1);
                pair(eq.w, kxy, w2, sD0); pair(eq.w, kzw, w2, sD1);
            };

            float4 kv0 = ek4[(size_t)h0 * (TK / 4) + l];        // depth-2 prefetch
            float4 kv1 = ek4[(size_t)(h0 + 1) * (TK / 4) + l];
            #pragma unroll 2
            for (int hh = 0; hh < H_ / NW - 2; ++hh) {
                float4 kvn = ek4[(size_t)(h0 + hh + 2) * (TK / 4) + l];
                body(h0 + hh, kv0);
                kv0 = kv1; kv1 = kvn;
            }
            body(h0 + H_ / NW - 2, kv0);
            body(h0 + H_ / NW - 1, kv1);

            ((float4*)&scoreP[w][0][0])[l] = make_float4(sA0.x, sA0.y, sA1.x, sA1.y);
            ((float4*)&scoreP[w][1][0])[l] = make_float4(sB0.x, sB0.y, sB1.x, sB1.y);
            ((float4*)&scoreP[w][2][0])[l] = make_float4(sC0.x, sC0.y, sC1.x, sC1.y);
            ((float4*)&scoreP[w][3][0])[l] = make_float4(sD0.x, sD0.y, sD1.x, sD1.y);
        } else {
            // ---- narrow (vl<=128): lane l covers k=2l,2l+1; half per-iter work.
            // scoreP for k>=128 is never written; phase 2 masks (k>=vl -> NEG)
            // BEFORE use, and cndmask is NaN-safe on garbage.
            const float2* ek2 = (const float2*)(EkT + (size_t)b * H_ * TK);
            v2f sA={0,0}, sB={0,0}, sC={0,0}, sD={0,0};

            auto body = [&](int h, float2 kvf) {
                float4 eq  = eqb[h];                   // uniform -> s_load_dwordx4
                float  wvh = wv[h];                    // uniform -> s_load_dword
                v2f w2 = {wvh, wvh};
                v2f k2 = {kvf.x, kvf.y};
                pair(eq.x, k2, w2, sA);
                pair(eq.y, k2, w2, sB);
                pair(eq.z, k2, w2, sC);
                pair(eq.w, k2, w2, sD);
            };

            float2 kv0 = ek2[(size_t)h0 * (TK / 2) + l];        // depth-2 prefetch
            float2 kv1 = ek2[(size_t)(h0 + 1) * (TK / 2) + l];
            #pragma unroll 2
            for (int hh = 0; hh < H_ / NW - 2; ++hh) {
                float2 kvn = ek2[(size_t)(h0 + hh + 2) * (TK / 2) + l];
                body(h0 + hh, kv0);
                kv0 = kv1; kv1 = kvn;
            }
            body(h0 + H_ / NW - 2, kv0);
            body(h0 + H_ / NW - 1, kv1);

            ((float2*)&scoreP[w][0][0])[l] = make_float2(sA.x, sA.y);
            ((float2*)&scoreP[w][1][0])[l] = make_float2(sB.x, sB.y);
            ((float2*)&scoreP[w][2][0])[l] = make_float2(sC.x, sC.y);
            ((float2*)&scoreP[w][3][0])[l] = make_float2(sD.x, sD.y);
        }
    }
    __syncthreads();

    // ---- phase 2: wave r (r<QT) softmaxes row q0+r; lane covers k=4l..4l+3 ----
    if (t < 64 * QT) {
        int r = w;
        // W = sum_h wv_h; score = W - 2*sum(wv*r)
        float W = waveSum(wv[l] + wv[l + 64] + wv[l + 128] + wv[l + 192]);
        float4 v = {0, 0, 0, 0};
        #pragma unroll
        for (int s = 0; s < NW; ++s) {
            float4 ps = ((const float4*)&scoreP[s][r][0])[l];
            v.x += ps.x; v.y += ps.y; v.z += ps.z; v.w += ps.w;
        }
        int k0 = 4 * l;
        v.x = (k0     < vl) ? fmaf(-2.f, v.x, W) : NEG;   // mask BEFORE use (NaN-safe)
        v.y = (k0 + 1 < vl) ? fmaf(-2.f, v.y, W) : NEG;
        v.z = (k0 + 2 < vl) ? fmaf(-2.f, v.z, W) : NEG;
        v.w = (k0 + 3 < vl) ? fmaf(-2.f, v.w, W) : NEG;
        float m  = waveMax(fmaxf(fmaxf(v.x, v.y), fmaxf(v.z, v.w)));
        // vl>0: masked p underflows to exactly 0 (matches ref). vl==0: uniform.
        float p0 = fast_exp2((v.x - m) * LOG2E);
        float p1 = fast_exp2((v.y - m) * LOG2E);
        float p2 = fast_exp2((v.z - m) * LOG2E);
        float p3 = fast_exp2((v.w - m) * LOG2E);
        float dr = fast_rcp(waveSum(p0 + p1 + p2 + p3));
        attnT[k0    ][r] = p0 * dr;
        attnT[k0 + 1][r] = p1 * dr;
        attnT[k0 + 2][r] = p2 * dr;
        attnT[k0 + 3][r] = p3 * dr;
    }
    __syncthreads();

    // ---- phase 3: half-block splits k-range, clipped to vl (weights for k>=vl are 0) ----
    {
        int half = t >> 8, v = t & 255;
        int kLim = (vl == 0) ? TK : vl;        // vl==0: uniform weights over all k
        int kBeg = half * (TK / 2);
        int kEnd = min(kBeg + TK / 2, kLim);   // half1 empty when kLim<=128
        const float*  vcol = values + (size_t)b * TK * DV + v;
        const float4* at4  = (const float4*)attnT;
        float o0 = 0.f, o1 = 0.f, o2 = 0.f, o3 = 0.f;
        #pragma unroll 4
        for (int k = kBeg; k < kEnd; ++k) {
            float  vv = vcol[k * DV];          // coalesced over v
            float4 a  = at4[k];                // broadcast b128
            o0 = fmaf(a.x, vv, o0);
            o1 = fmaf(a.y, vv, o1);
            o2 = fmaf(a.z, vv, o2);
            o3 = fmaf(a.w, vv, o3);
        }
        if (half == 1) {                       // stash partials (reuse scoreP[0])
            scoreP[0][0][v] = o0;
            scoreP[0][1][v] = o1;
            scoreP[0][2][v] = o2;
            scoreP[0][3][v] = o3;
        }
        __syncthreads();
        if (half == 0) {
            float* orow = out + (size_t)(b * TQ + q0) * DV + v;
            orow[0]      = o0 + scoreP[0][0][v];
            orow[DV]     = o1 + scoreP[0][1][v];
            orow[2 * DV] = o2 + scoreP[0][2][v];
            orow[3 * DV] = o3 + scoreP[0][3][v];
        }
    }
}

extern "C" void kernel_launch(void* const* d_in, const int* in_sizes, int n_in,
                              void* d_out, int out_size, void* d_ws, size_t ws_size,
                              hipStream_t stream) {
    const float* queries    = (const float*)d_in[0];
    const float* keys       = (const float*)d_in[1];
    const float* values     = (const float*)d_in[2];
    const int*   valid_lens = (const int*)  d_in[3];
    const float* wq         = (const float*)d_in[4];
    const float* wk         = (const float*)d_in[5];
    const float* wv         = (const float*)d_in[6];
    float* out = (float*)d_out;

    float*  EkT = (float*)d_ws;                          // [B,H,TK]   = 4 MiB
    float4* EqW = (float4*)(EkT + (size_t)B_ * H_ * TK); // [B,32,H]x4 = 2 MiB

    proj_kernel<<<1024, 256, 0, stream>>>(keys, wk, queries, wq, EkT, EqW, valid_lens);
    attn_kernel<<<B_ * (TQ / QT), 512, 0, stream>>>(EqW, EkT, values,
                                                    valid_lens, wv, out);
}